// Round 1
// baseline (501.722 us; speedup 1.0000x reference)
//
#include <hip/hip_runtime.h>
#include <hip/hip_bf16.h>

#define V_  5
#define B_  2
#define C_  32
#define H_  128
#define W_  160
#define D_  32
#define G_  8
#define HW_  (H_*W_)
#define DHW_ (D_*HW_)

// ---------------- projection setup ----------------

__device__ inline void combine_mat(const float* m, float out[4][4]) {
    const float* ext = m;        // [4][4]
    const float* K   = m + 16;   // [4][4]
    #pragma unroll
    for (int r = 0; r < 4; ++r)
        #pragma unroll
        for (int c = 0; c < 4; ++c)
            out[r][c] = ext[r*4 + c];
    // top 3x4 = K[:3,:3] @ ext[:3,:4]
    #pragma unroll
    for (int r = 0; r < 3; ++r)
        #pragma unroll
        for (int c = 0; c < 4; ++c) {
            float s = 0.f;
            #pragma unroll
            for (int k = 0; k < 3; ++k) s += K[r*4 + k] * ext[k*4 + c];
            out[r][c] = s;
        }
}

__device__ inline void invert4(const float Ain[4][4], float Inv[4][4]) {
    float A[4][4];
    #pragma unroll
    for (int r = 0; r < 4; ++r)
        #pragma unroll
        for (int c = 0; c < 4; ++c) {
            A[r][c]   = Ain[r][c];
            Inv[r][c] = (r == c) ? 1.f : 0.f;
        }
    for (int k = 0; k < 4; ++k) {
        // partial pivot
        int p = k; float best = fabsf(A[k][k]);
        for (int r = k + 1; r < 4; ++r) {
            float v = fabsf(A[r][k]);
            if (v > best) { best = v; p = r; }
        }
        if (p != k) {
            for (int j = 0; j < 4; ++j) {
                float t = A[k][j]; A[k][j] = A[p][j]; A[p][j] = t;
                t = Inv[k][j]; Inv[k][j] = Inv[p][j]; Inv[p][j] = t;
            }
        }
        float dinv = 1.f / A[k][k];
        for (int j = 0; j < 4; ++j) { A[k][j] *= dinv; Inv[k][j] *= dinv; }
        for (int r = 0; r < 4; ++r) {
            if (r == k) continue;
            float f = A[r][k];
            for (int j = 0; j < 4; ++j) {
                A[r][j]  -= f * A[k][j];
                Inv[r][j] -= f * Inv[k][j];
            }
        }
    }
}

// proj_ws layout: [b][v-1][12]  (rows 0..2 of the 4x4: R00 R01 R02 t0 | R10.. t1 | R20.. t2)
__global__ void k_proj(const float* __restrict__ pm, float* __restrict__ proj_ws) {
    int b = threadIdx.x;
    if (b >= B_) return;
    float C0[4][4], C0inv[4][4];
    combine_mat(pm + (b * V_ + 0) * 32, C0);
    invert4(C0, C0inv);
    for (int v = 1; v < V_; ++v) {
        float Cv[4][4];
        combine_mat(pm + (b * V_ + v) * 32, Cv);
        float* o = proj_ws + (b * 4 + (v - 1)) * 12;
        #pragma unroll
        for (int r = 0; r < 3; ++r)
            #pragma unroll
            for (int c = 0; c < 4; ++c) {
                float s = 0.f;
                #pragma unroll
                for (int k = 0; k < 4; ++k) s += Cv[r][k] * C0inv[k][c];
                o[r*4 + c] = s;
            }
    }
}

// ---------------- main fused kernel ----------------
// grid (W/32, H, B), block (32 w, 32 d)
__global__ __launch_bounds__(1024) void k_main(
    const float* __restrict__ feat,     // [V][B][C][H][W]
    const float* __restrict__ depthv,   // [B][D][H][W]
    const float* __restrict__ pw_w1, const float* __restrict__ pw_b1,
    const float* __restrict__ pw_w2, const float* __restrict__ pw_b2,
    const float* __restrict__ pw_w3, const float* __restrict__ pw_b3,
    const float* __restrict__ proj_ws,
    float* __restrict__ out_vw,         // [B][4][H][W]
    float* __restrict__ out_sim)        // [B][G][D][H][W]
{
    const int tx = threadIdx.x;          // w within tile
    const int ty = threadIdx.y;          // d
    const int w0 = blockIdx.x * 32;
    const int h  = blockIdx.y;
    const int b  = blockIdx.z;
    const int w  = w0 + tx;
    const int tid = ty * 32 + tx;

    __shared__ float ref_s[C_][32];      // ref features, [channel][w]
    __shared__ float red[32][32];        // sigmoid values, [d][w]
    __shared__ float vw_s[32];
    __shared__ float pw_s[177];          // 0:16 w1 | 16:32 b1 | 32:160 w2 | 160:168 b2 | 168:176 w3 | 176 b3
    __shared__ float proj_s[48];         // 4 views x 12

    ref_s[ty][tx] = feat[(b * C_ + ty) * HW_ + h * W_ + w];   // view 0
    if (tid < 16)        pw_s[tid] = pw_w1[tid];
    else if (tid < 32)   pw_s[tid] = pw_b1[tid - 16];
    else if (tid < 160)  pw_s[tid] = pw_w2[tid - 32];
    else if (tid < 168)  pw_s[tid] = pw_b2[tid - 160];
    else if (tid < 176)  pw_s[tid] = pw_w3[tid - 168];
    else if (tid == 176) pw_s[tid] = pw_b3[0];
    if (tid >= 256 && tid < 304) proj_s[tid - 256] = proj_ws[b * 48 + (tid - 256)];
    __syncthreads();

    const int d = ty;
    const float depth = depthv[(b * D_ + d) * HW_ + h * W_ + w];
    const float xf = (float)w, yf = (float)h;

    float simsum[G_];
    #pragma unroll
    for (int g = 0; g < G_; ++g) simsum[g] = 0.f;
    float wsum = 0.f;

    for (int v = 1; v < V_; ++v) {
        const float* P = &proj_s[(v - 1) * 12];
        float px = (P[0]*xf + P[1]*yf + P[2])  * depth + P[3];
        float py = (P[4]*xf + P[5]*yf + P[6])  * depth + P[7];
        float pz = (P[8]*xf + P[9]*yf + P[10]) * depth + P[11];
        float xs = px / pz;
        float ys = py / pz;

        float x0 = floorf(xs), y0 = floorf(ys);
        float wx1 = xs - x0,  wy1 = ys - y0;
        float wx0 = 1.f - wx1, wy0 = 1.f - wy1;

        bool vx0 = (x0 >= 0.f)       && (x0 <= (float)(W_-1));
        bool vx1 = (x0+1.f >= 0.f)   && (x0+1.f <= (float)(W_-1));
        bool vy0 = (y0 >= 0.f)       && (y0 <= (float)(H_-1));
        bool vy1 = (y0+1.f >= 0.f)   && (y0+1.f <= (float)(H_-1));

        int xc0 = (int)fminf(fmaxf(x0,      0.f), (float)(W_-1));
        int xc1 = (int)fminf(fmaxf(x0+1.f,  0.f), (float)(W_-1));
        int yc0 = (int)fminf(fmaxf(y0,      0.f), (float)(H_-1));
        int yc1 = (int)fminf(fmaxf(y0+1.f,  0.f), (float)(H_-1));

        float w00 = (vx0 && vy0) ? (wx0 * wy0) : 0.f;
        float w01 = (vx1 && vy0) ? (wx1 * wy0) : 0.f;
        float w10 = (vx0 && vy1) ? (wx0 * wy1) : 0.f;
        float w11 = (vx1 && vy1) ? (wx1 * wy1) : 0.f;

        const int o00 = yc0 * W_ + xc0;
        const int o01 = yc0 * W_ + xc1;
        const int o10 = yc1 * W_ + xc0;
        const int o11 = yc1 * W_ + xc1;

        const float* fb = feat + ((v * B_ + b) * C_) * HW_;

        float sim[G_];
        #pragma unroll
        for (int g = 0; g < G_; ++g) sim[g] = 0.f;

        #pragma unroll 8
        for (int c = 0; c < C_; ++c) {
            const float* fc = fb + c * HW_;
            float val = w00 * fc[o00] + w01 * fc[o01] + w10 * fc[o10] + w11 * fc[o11];
            sim[c >> 2] += val * ref_s[c][tx];
        }
        #pragma unroll
        for (int g = 0; g < G_; ++g) sim[g] *= 0.25f;

        // softmax over G + entropy
        float m = sim[0];
        #pragma unroll
        for (int g = 1; g < G_; ++g) m = fmaxf(m, sim[g]);
        float e[G_]; float es = 0.f;
        #pragma unroll
        for (int g = 0; g < G_; ++g) { e[g] = expf(sim[g] - m); es += e[g]; }
        float inv_es = 1.f / es;
        float ent = 0.f;
        #pragma unroll
        for (int g = 0; g < G_; ++g) {
            float p = e[g] * inv_es;
            ent -= p * logf(p + 1e-7f);
        }

        // pixelwise MLP: 1 -> 16 -> 8 -> 1
        float h2[8];
        #pragma unroll
        for (int j = 0; j < 8; ++j) h2[j] = pw_s[160 + j];
        #pragma unroll
        for (int k = 0; k < 16; ++k) {
            float h1 = fmaxf(ent * pw_s[k] + pw_s[16 + k], 0.f);
            #pragma unroll
            for (int j = 0; j < 8; ++j) h2[j] += pw_s[32 + j*16 + k] * h1;
        }
        float o3 = pw_s[176];
        #pragma unroll
        for (int j = 0; j < 8; ++j) o3 += pw_s[168 + j] * fmaxf(h2[j], 0.f);
        float sig = 1.f / (1.f + expf(-o3));

        // max over d (per pixel)
        red[ty][tx] = sig;
        __syncthreads();
        if (ty == 0) {
            float mv = red[0][tx];
            #pragma unroll
            for (int k = 1; k < 32; ++k) mv = fmaxf(mv, red[k][tx]);
            vw_s[tx] = mv;
            out_vw[(b * 4 + (v - 1)) * HW_ + h * W_ + w] = mv;
        }
        __syncthreads();
        float vw = vw_s[tx];

        #pragma unroll
        for (int g = 0; g < G_; ++g) simsum[g] += sim[g] * vw;
        wsum += vw;
    }

    float wn = 1.f / (wsum + 1e-6f);
    float* so = out_sim + (b * G_) * DHW_ + d * HW_ + h * W_ + w;
    #pragma unroll
    for (int g = 0; g < G_; ++g) so[g * DHW_] = simsum[g] * wn;
}

// ---------------- conv3d 3x3x3, pad 1 ----------------
// grid (W/32, H/8, B*D), block (32, 8)
__global__ __launch_bounds__(256) void k_conv1(
    const float* __restrict__ in,   // [B][8][D][H][W]
    const float* __restrict__ wgt,  // [8][8][27]
    const float* __restrict__ bias, // [8]
    float* __restrict__ out)        // [B][8][D][H][W]
{
    __shared__ float in_s[8][3][10][34];
    __shared__ float w_s[1728];
    const int tx = threadIdx.x, ty = threadIdx.y;
    const int tid = ty * 32 + tx;
    const int w0 = blockIdx.x * 32;
    const int h0 = blockIdx.y * 8;
    const int bd = blockIdx.z;
    const int b = bd >> 5, d = bd & 31;

    for (int i = tid; i < 1728; i += 256) w_s[i] = wgt[i];
    for (int i = tid; i < 8*3*10*34; i += 256) {
        int wx = i % 34; int r = i / 34;
        int hy = r % 10; r /= 10;
        int dz = r % 3;  int ic = r / 3;
        int gw = w0 + wx - 1, gh = h0 + hy - 1, gd = d + dz - 1;
        float val = 0.f;
        if (gw >= 0 && gw < W_ && gh >= 0 && gh < H_ && gd >= 0 && gd < D_)
            val = in[((b * 8 + ic) * D_ + gd) * HW_ + gh * W_ + gw];
        in_s[ic][dz][hy][wx] = val;
    }
    __syncthreads();

    float acc[8];
    #pragma unroll
    for (int oc = 0; oc < 8; ++oc) acc[oc] = bias[oc];

    #pragma unroll
    for (int ic = 0; ic < 8; ++ic)
        #pragma unroll
        for (int dz = 0; dz < 3; ++dz)
            #pragma unroll
            for (int hy = 0; hy < 3; ++hy)
                #pragma unroll
                for (int wx = 0; wx < 3; ++wx) {
                    float v = in_s[ic][dz][ty + hy][tx + wx];
                    const float* wp = w_s + (ic * 3 + dz) * 9 + hy * 3 + wx;
                    #pragma unroll
                    for (int oc = 0; oc < 8; ++oc) acc[oc] += v * wp[oc * 216];
                }

    float* op = out + (b * 8) * DHW_ + d * HW_ + (h0 + ty) * W_ + (w0 + tx);
    #pragma unroll
    for (int oc = 0; oc < 8; ++oc) op[oc * DHW_] = fmaxf(acc[oc], 0.f);
}

__global__ __launch_bounds__(256) void k_conv2(
    const float* __restrict__ in,   // [B][8][D][H][W]
    const float* __restrict__ wgt,  // [1][8][27]
    const float* __restrict__ bias, // [1]
    float* __restrict__ out)        // [B][D][H][W]
{
    __shared__ float in_s[8][3][10][34];
    __shared__ float w_s[216];
    const int tx = threadIdx.x, ty = threadIdx.y;
    const int tid = ty * 32 + tx;
    const int w0 = blockIdx.x * 32;
    const int h0 = blockIdx.y * 8;
    const int bd = blockIdx.z;
    const int b = bd >> 5, d = bd & 31;

    if (tid < 216) w_s[tid] = wgt[tid];
    for (int i = tid; i < 8*3*10*34; i += 256) {
        int wx = i % 34; int r = i / 34;
        int hy = r % 10; r /= 10;
        int dz = r % 3;  int ic = r / 3;
        int gw = w0 + wx - 1, gh = h0 + hy - 1, gd = d + dz - 1;
        float val = 0.f;
        if (gw >= 0 && gw < W_ && gh >= 0 && gh < H_ && gd >= 0 && gd < D_)
            val = in[((b * 8 + ic) * D_ + gd) * HW_ + gh * W_ + gw];
        in_s[ic][dz][hy][wx] = val;
    }
    __syncthreads();

    float acc = bias[0];
    #pragma unroll
    for (int ic = 0; ic < 8; ++ic)
        #pragma unroll
        for (int dz = 0; dz < 3; ++dz)
            #pragma unroll
            for (int hy = 0; hy < 3; ++hy)
                #pragma unroll
                for (int wx = 0; wx < 3; ++wx)
                    acc += in_s[ic][dz][ty + hy][tx + wx] * w_s[(ic * 3 + dz) * 9 + hy * 3 + wx];

    out[(b * D_ + d) * HW_ + (h0 + ty) * W_ + (w0 + tx)] = acc;
}

// ---------------- final: softmax over D, depth, confidence ----------------
__global__ __launch_bounds__(256) void k_final(
    const float* __restrict__ pvp,     // [B][D][H][W]
    const float* __restrict__ depthv,  // [B][D][H][W]
    float* __restrict__ out_depth,     // [B][H][W]
    float* __restrict__ out_conf)      // [B][H][W]
{
    int i = blockIdx.x * 256 + threadIdx.x;
    if (i >= B_ * HW_) return;
    int b = i / HW_;
    int p = i - b * HW_;

    const float* pp = pvp + b * DHW_ + p;
    const float* dv = depthv + b * DHW_ + p;

    float x[D_];
    float m = -3.4e38f;
    #pragma unroll
    for (int d = 0; d < D_; ++d) { x[d] = pp[d * HW_]; m = fmaxf(m, x[d]); }
    float s = 0.f;
    #pragma unroll
    for (int d = 0; d < D_; ++d) { x[d] = expf(x[d] - m); s += x[d]; }
    float inv = 1.f / s;

    float dep = 0.f, fd = 0.f;
    #pragma unroll
    for (int d = 0; d < D_; ++d) {
        float pv = x[d] * inv;
        x[d] = pv;
        dep += pv * dv[d * HW_];
        fd  += pv * (float)d;
    }
    int di = (int)fd;
    di = di < 0 ? 0 : (di > D_ - 1 ? D_ - 1 : di);
    float conf = 0.f;
    #pragma unroll
    for (int k = 0; k < 4; ++k) {
        int idx = di - 1 + k;
        if (idx >= 0 && idx < D_) conf += x[idx];
    }
    out_depth[i] = dep;
    out_conf[i]  = conf;
}

// ---------------- launch ----------------
extern "C" void kernel_launch(void* const* d_in, const int* in_sizes, int n_in,
                              void* d_out, int out_size, void* d_ws, size_t ws_size,
                              hipStream_t stream) {
    const float* feat   = (const float*)d_in[0];
    const float* pm     = (const float*)d_in[1];
    const float* depthv = (const float*)d_in[2];
    const float* reg_w1 = (const float*)d_in[3];
    const float* reg_b1 = (const float*)d_in[4];
    const float* reg_w2 = (const float*)d_in[5];
    const float* reg_b2 = (const float*)d_in[6];
    const float* pw_w1  = (const float*)d_in[7];
    const float* pw_b1  = (const float*)d_in[8];
    const float* pw_w2  = (const float*)d_in[9];
    const float* pw_b2  = (const float*)d_in[10];
    const float* pw_w3  = (const float*)d_in[11];
    const float* pw_b3  = (const float*)d_in[12];

    float* out = (float*)d_out;
    float* out_depth = out;                       // B*H*W      = 40960
    float* out_conf  = out + B_*HW_;              // 40960
    float* out_vw    = out + 2*B_*HW_;            // B*4*H*W    = 163840
    float* out_pvp   = out_vw + B_*4*HW_;         // B*D*H*W    = 1310720
    float* out_sim   = out_pvp + B_*DHW_;         // B*G*D*H*W  = 10485760

    float* ws      = (float*)d_ws;
    float* proj_ws = ws;          // 96 floats
    float* hid     = ws + 128;    // B*8*D*H*W = 10485760 floats

    hipLaunchKernelGGL(k_proj, dim3(1), dim3(64), 0, stream, pm, proj_ws);

    hipLaunchKernelGGL(k_main, dim3(W_/32, H_, B_), dim3(32, 32), 0, stream,
                       feat, depthv, pw_w1, pw_b1, pw_w2, pw_b2, pw_w3, pw_b3,
                       proj_ws, out_vw, out_sim);

    hipLaunchKernelGGL(k_conv1, dim3(W_/32, H_/8, B_*D_), dim3(32, 8), 0, stream,
                       out_sim, reg_w1, reg_b1, hid);

    hipLaunchKernelGGL(k_conv2, dim3(W_/32, H_/8, B_*D_), dim3(32, 8), 0, stream,
                       hid, reg_w2, reg_b2, out_pvp);

    hipLaunchKernelGGL(k_final, dim3((B_*HW_ + 255)/256), dim3(256), 0, stream,
                       out_pvp, depthv, out_depth, out_conf);
}